// Round 7
// baseline (331.981 us; speedup 1.0000x reference)
//
#include <hip/hip_runtime.h>

typedef unsigned short u16;
typedef unsigned int u32;
typedef u16 u16x4 __attribute__((ext_vector_type(4)));
typedef u16 u16x8 __attribute__((ext_vector_type(8)));
typedef u32 u32x4 __attribute__((ext_vector_type(4)));
typedef __bf16 bf16x8 __attribute__((ext_vector_type(8)));
typedef float f32x16 __attribute__((ext_vector_type(16)));

#define NB   2
#define NQH  32
#define NKH  8
#define SEQ  2048
#define DIM  128
#define QT   128                      // q rows per block (32 per wave, 32x32 MFMA)
#define NHALF   64                    // 32-key half-tiles per head
#define HALFU16 4096                  // 32*128 u16 = 8KB per half image
#define TILEU16 (2 * HALFU16)
#define VOFFU16 (16 * 32 * TILEU16)   // V images after 16 heads * 32 tiles of K

__device__ __forceinline__ u16 f2bf(float f) {
  u32 u = __builtin_bit_cast(u32, f);
  u += 0x7FFFu + ((u >> 16) & 1u);
  return (u16)(u >> 16);
}
__device__ __forceinline__ u32 cvtpk(float lo, float hi) {
  u32 r;
  asm("v_cvt_pk_bf16_f32 %0, %1, %2" : "=v"(r) : "v"(lo), "v"(hi));
  return r;
}
__device__ __forceinline__ f32x16 mfma32(u16x8 a, u16x8 b, f32x16 c) {
  return __builtin_amdgcn_mfma_f32_32x32x16_bf16(
      __builtin_bit_cast(bf16x8, a), __builtin_bit_cast(bf16x8, b), c, 0, 0, 0);
}
__device__ __forceinline__ void gl_lds16(const u16* g, u16* l) {
  __builtin_amdgcn_global_load_lds(
      (const __attribute__((address_space(1))) u32*)(const void*)g,
      (__attribute__((address_space(3))) u32*)(void*)l, 16, 0, 0);
}

// ---- pre-pass: swizzled bf16 images ----
// K tile image (as before; a 32-row half is a contiguous 4096-u16 slice):
//   u16 idx j*128 + (dm ^ ((j&7)<<3)) = bf16 K[j][dm]
// V half image [128][32]: u16 idx d*32 + 8*gr' + i, gr' = gr ^ ((d>>1)&3),
//   slot p = 8*gr+i holds key kappa(p) = swap bits 2<->3 of p (5-bit).
__global__ __launch_bounds__(256) void prep(const float* __restrict__ Kg,
                                            const float* __restrict__ Vg,
                                            u16* __restrict__ ws) {
  const int bid = blockIdx.x;          // 0..1023 : first 512 K, next 512 V
  const int tid = threadIdx.x;
  const int tile = bid & 511;          // bkh*32 + kt
  const size_t sbase = (size_t)(tile >> 5) * SEQ * DIM + (size_t)(tile & 31) * 64 * DIM;
  if (bid < 512) {
    const float* src = Kg + sbase;
    u16* img = ws + (size_t)tile * TILEU16;
    #pragma unroll
    for (int u = 0; u < 8; ++u) {
      int c = tid + 256 * u;           // float4 chunk 0..2047
      int j = c >> 5;
      int dm = (c & 31) * 4;
      float4 v = *(const float4*)(src + j * DIM + dm);
      u16x4 w = { f2bf(v.x), f2bf(v.y), f2bf(v.z), f2bf(v.w) };
      *(u16x4*)(img + j * 128 + (dm ^ ((j & 7) << 3))) = w;
    }
  } else {
    const float* src = Vg + sbase;
    u16* img = ws + VOFFU16 + (size_t)tile * TILEU16;
    #pragma unroll
    for (int u = 0; u < 4; ++u) {
      int g = tid + 256 * u;           // granule 0..1023 (8 u16 each)
      int half = g >> 9;
      int gg = g & 511;
      int d = gg >> 2;
      int grp = gg & 3;                // stored granule slot gr'
      int gr = grp ^ ((d >> 1) & 3);   // logical granule (slots 8gr..8gr+7)
      u16x8 w;
      #pragma unroll
      for (int i = 0; i < 8; ++i) {
        int p = 8 * gr + i;
        int key = (p & ~12) | ((p & 8) >> 1) | ((p & 4) << 1);  // swap bits 2,3
        w[i] = f2bf(src[(32 * half + key) * DIM + d]);
      }
      *(u16x8*)(img + half * HALFU16 + d * 32 + grp * 8) = w;
    }
  }
}

__global__ __launch_bounds__(256) void gqa_fwd(const float* __restrict__ Qg,
                                               const u16* __restrict__ ws,
                                               float* __restrict__ Og) {
  __shared__ __align__(16) u16 sK[2][HALFU16];
  __shared__ __align__(16) u16 sV[2][HALFU16];

  const int tid  = threadIdx.x;
  const int lane = tid & 63;
  const int wave = tid >> 6;
  const int l31  = lane & 31;
  const int h    = lane >> 5;

  // XCD-aware swizzle: grid = 1024, 8 XCDs -> contiguous runs of 128.
  const int id = blockIdx.x;           // 0..1023
  const int wg = (id & 7) * 128 + (id >> 3);
  const int qtile = wg & 15;           // 0..15
  const int bqh   = wg >> 4;           // 0..63
  const int b     = bqh >> 5;
  const int qh    = bqh & 31;
  const int kh    = qh >> 2;           // G = 4

  const size_t qbase = (size_t)bqh * SEQ * DIM;
  const u16* imgK = ws + (size_t)((b * NKH + kh) * 32) * TILEU16;
  const u16* imgV = imgK + VOFFU16;
  const int qrow_w = qtile * QT + wave * 32;

  // log2-domain scale: 1/sqrt(128) * log2(e)
  const float s2 = 0.08838834764831845f * 1.4426950408889634f;

  // Q frags (B-operand 32x32x16): qf[s8][e] = Q[q=l31][d=16*s8+8*h+e] * s2
  u16x8 qf[8];
  #pragma unroll
  for (int s8 = 0; s8 < 8; ++s8) {
    const float* qp = Qg + qbase + (size_t)(qrow_w + l31) * DIM + 16 * s8 + 8 * h;
    float4 a = *(const float4*)qp;
    float4 c = *(const float4*)(qp + 4);
    qf[s8] = __builtin_bit_cast(u16x8, u32x4{
        cvtpk(a.x * s2, a.y * s2), cvtpk(a.z * s2, a.w * s2),
        cvtpk(c.x * s2, c.y * s2), cvtpk(c.z * s2, c.w * s2) });
  }

  f32x16 oacc[4];
  #pragma unroll
  for (int dt = 0; dt < 4; ++dt)
    #pragma unroll
    for (int r = 0; r < 16; ++r) oacc[dt][r] = 0.f;
  float mrow = -3.0e38f, lrow = 0.f;

  const int swzK = (l31 & 7) << 3;
  const int swzV = ((l31 >> 1) & 3) << 3;

  auto issue = [&](int hn, int pb) {
    const u16* gK = imgK + (size_t)hn * HALFU16;
    const u16* gV = imgV + (size_t)hn * HALFU16;
    gl_lds16(gK + wave * 512 + lane * 8,       &sK[pb][wave * 512]);
    gl_lds16(gK + (wave + 4) * 512 + lane * 8, &sK[pb][(wave + 4) * 512]);
    gl_lds16(gV + wave * 512 + lane * 8,       &sV[pb][wave * 512]);
    gl_lds16(gV + (wave + 4) * 512 + lane * 8, &sV[pb][(wave + 4) * 512]);
  };

  auto half_body = [&](int H, int PB) {
    issue((H + 1) & (NHALF - 1), PB ^ 1);   // prefetch next half
    asm volatile("s_waitcnt vmcnt(4)" ::: "memory");  // this half's 4 loads done
    __builtin_amdgcn_s_barrier();           // keep prefetch in flight

    // ---- S^T = K Q^T, two independent 4-chains over d
    f32x16 sA, sB;
    #pragma unroll
    for (int r = 0; r < 16; ++r) { sA[r] = 0.f; sB[r] = 0.f; }
    __builtin_amdgcn_s_setprio(1);
    #pragma unroll
    for (int s8 = 0; s8 < 4; ++s8) {
      u16x8 kfA = *(const u16x8*)&sK[PB][l31 * 128 + ((16 * s8 + 8 * h) ^ swzK)];
      u16x8 kfB = *(const u16x8*)&sK[PB][l31 * 128 + ((16 * (s8 + 4) + 8 * h) ^ swzK)];
      sA = mfma32(kfA, qf[s8], sA);
      sB = mfma32(kfB, qf[s8 + 4], sB);
    }
    __builtin_amdgcn_s_setprio(0);
    f32x16 sac = sA + sB;   // sac[r] = S[key=(r&3)+8*(r>>2)+4*h][q=l31]

    // ---- online softmax (log2 domain), q-row = l31
    float tmax = -3.0e38f;
    #pragma unroll
    for (int r = 0; r < 16; ++r) tmax = fmaxf(tmax, sac[r]);
    tmax = fmaxf(tmax, __shfl_xor(tmax, 32, 64));

    if (!__all(tmax - mrow <= 11.0f)) {     // defer-max (P bounded by 2^11)
      float mn = fmaxf(mrow, tmax);
      float corr = exp2f(mrow - mn);
      mrow = mn;
      lrow *= corr;
      #pragma unroll
      for (int r = 0; r < 16; ++r) {
        float co = __shfl(corr, (r & 3) + 8 * (r >> 2) + 4 * h, 64);
        oacc[0][r] *= co; oacc[1][r] *= co; oacc[2][r] *= co; oacc[3][r] *= co;
      }
    }

    float rsum = 0.f;
    #pragma unroll
    for (int r = 0; r < 16; ++r) {
      sac[r] = exp2f(sac[r] - mrow);
      rsum += sac[r];
    }
    rsum += __shfl_xor(rsum, 32, 64);
    lrow += rsum;

    // ---- A-frags: pure bitcast (sigma' folded into V image)
    u16x8 af[2];
    af[0] = __builtin_bit_cast(u16x8, u32x4{cvtpk(sac[0], sac[1]),  cvtpk(sac[2], sac[3]),
                                            cvtpk(sac[4], sac[5]),  cvtpk(sac[6], sac[7])});
    af[1] = __builtin_bit_cast(u16x8, u32x4{cvtpk(sac[8], sac[9]),  cvtpk(sac[10], sac[11]),
                                            cvtpk(sac[12], sac[13]), cvtpk(sac[14], sac[15])});

    // ---- O += P V : vf = V^T half image row d=32*dt+l31, slots 16c+8h
    __builtin_amdgcn_s_setprio(1);
    #pragma unroll
    for (int dt = 0; dt < 4; ++dt) {
      #pragma unroll
      for (int c = 0; c < 2; ++c) {
        u16x8 vf = *(const u16x8*)&sV[PB][(32 * dt + l31) * 32 + ((16 * c + 8 * h) ^ swzV)];
        oacc[dt] = mfma32(af[c], vf, oacc[dt]);
      }
    }
    __builtin_amdgcn_s_setprio(0);
    __builtin_amdgcn_s_barrier();           // all waves done reading buf[PB]
  };

  issue(0, 0);
  for (int H2 = 0; H2 < NHALF / 2; ++H2) {
    half_body(2 * H2, 0);
    half_body(2 * H2 + 1, 1);
  }
  asm volatile("s_waitcnt vmcnt(0)" ::: "memory");  // drain wrap-around prefetch

  // ---- epilogue: O[q = qrow_w+(r&3)+8*(r>>2)+4h][d = 32*dt + l31] / lrow
  float linv = 1.0f / lrow;
  #pragma unroll
  for (int r = 0; r < 16; ++r) {
    const int ql = (r & 3) + 8 * (r >> 2) + 4 * h;
    float li = __shfl(linv, ql, 64);
    float* op = Og + qbase + (size_t)(qrow_w + ql) * DIM + l31;
    op[0]  = oacc[0][r] * li;
    op[32] = oacc[1][r] * li;
    op[64] = oacc[2][r] * li;
    op[96] = oacc[3][r] * li;
  }
}

extern "C" void kernel_launch(void* const* d_in, const int* in_sizes, int n_in,
                              void* d_out, int out_size, void* d_ws, size_t ws_size,
                              hipStream_t stream) {
  const float* Q = (const float*)d_in[0];
  const float* K = (const float*)d_in[1];
  const float* V = (const float*)d_in[2];
  float* O = (float*)d_out;
  u16* ws = (u16*)d_ws;
  prep<<<dim3(1024), 256, 0, stream>>>(K, V, ws);
  gqa_fwd<<<dim3((SEQ / QT) * NB * NQH), 256, 0, stream>>>(Q, ws, O);
}

// Round 8
// 242.048 us; speedup vs baseline: 1.3716x; 1.3716x over previous
//
#include <hip/hip_runtime.h>

typedef unsigned short u16;
typedef unsigned int u32;
typedef u16 u16x4 __attribute__((ext_vector_type(4)));
typedef u16 u16x8 __attribute__((ext_vector_type(8)));
typedef u32 u32x4 __attribute__((ext_vector_type(4)));
typedef __bf16 bf16x8 __attribute__((ext_vector_type(8)));
typedef float f32x4 __attribute__((ext_vector_type(4)));

#define NB   2
#define NQH  32
#define NKH  8
#define SEQ  2048
#define DIM  128
#define QT   64                       // q rows per block (16 per wave, 16x16 MFMA)
#define NHALF   64                    // 32-key half-tiles per head
#define HALFU16 4096                  // 32*128 u16 = 8KB per half image
#define HEADU16 (NHALF * HALFU16)     // per-head image size (K or V)
#define VOFFU16 (16 * HEADU16)        // V images after 16 heads of K

__device__ __forceinline__ u16 f2bf(float f) {
  u32 u = __builtin_bit_cast(u32, f);
  u += 0x7FFFu + ((u >> 16) & 1u);
  return (u16)(u >> 16);
}
__device__ __forceinline__ u32 cvtpk(float lo, float hi) {
  u32 r;
  asm("v_cvt_pk_bf16_f32 %0, %1, %2" : "=v"(r) : "v"(lo), "v"(hi));
  return r;
}
__device__ __forceinline__ f32x4 mfma16(u16x8 a, u16x8 b, f32x4 c) {
  return __builtin_amdgcn_mfma_f32_16x16x32_bf16(
      __builtin_bit_cast(bf16x8, a), __builtin_bit_cast(bf16x8, b), c, 0, 0, 0);
}
__device__ __forceinline__ void gl_lds16(const u16* g, u16* l) {
  __builtin_amdgcn_global_load_lds(
      (const __attribute__((address_space(1))) u32*)(const void*)g,
      (__attribute__((address_space(3))) u32*)(void*)l, 16, 0, 0);
}

// ---- pre-pass: swizzled bf16 images ----
// K: per 64-key tile, u16 idx j*128 + (dm ^ ((j&7)<<3)) = K[j][dm]; a 32-key
//    half is a contiguous 4096-u16 slice (row&7 invariant under +32).
// V half image [128 d][32 slots]: u16 idx d*32 + 8*grp + i, grp = gr^((d>>1)&3),
//    slot s=8*gr+i holds key 16*(i>>2) + 4*gr + (i&3)  (sigma for 16x16 A-frag).
__global__ __launch_bounds__(256) void prep(const float* __restrict__ Kg,
                                            const float* __restrict__ Vg,
                                            u16* __restrict__ ws) {
  const int bid = blockIdx.x;          // 0..1023 : first 512 K, next 512 V
  const int tid = threadIdx.x;
  const int tile = bid & 511;          // head*32 + kt
  const size_t sbase = (size_t)(tile >> 5) * SEQ * DIM + (size_t)(tile & 31) * 64 * DIM;
  if (bid < 512) {
    const float* src = Kg + sbase;
    u16* img = ws + (size_t)tile * (2 * HALFU16);
    #pragma unroll
    for (int u = 0; u < 8; ++u) {
      int c = tid + 256 * u;           // float4 chunk 0..2047
      int j = c >> 5;
      int dm = (c & 31) * 4;
      float4 v = *(const float4*)(src + j * DIM + dm);
      u16x4 w = { f2bf(v.x), f2bf(v.y), f2bf(v.z), f2bf(v.w) };
      *(u16x4*)(img + j * 128 + (dm ^ ((j & 7) << 3))) = w;
    }
  } else {
    const float* src = Vg + sbase;
    u16* img = ws + VOFFU16 + (size_t)tile * (2 * HALFU16);
    #pragma unroll
    for (int u = 0; u < 4; ++u) {
      int g = tid + 256 * u;           // u16x8 granule 0..1023
      int half = g >> 9;
      int gg = g & 511;
      int d = gg >> 2;
      int grp = gg & 3;                // stored granule slot
      int gr = grp ^ ((d >> 1) & 3);   // logical lg group
      u16x8 w;
      #pragma unroll
      for (int i = 0; i < 8; ++i) {
        int key = 16 * (i >> 2) + 4 * gr + (i & 3);
        w[i] = f2bf(src[(32 * half + key) * DIM + d]);
      }
      *(u16x8*)(img + half * HALFU16 + d * 32 + grp * 8) = w;
    }
  }
}

__global__ __launch_bounds__(256) void gqa_fwd(const float* __restrict__ Qg,
                                               const u16* __restrict__ ws,
                                               float* __restrict__ Og) {
  __shared__ __align__(16) u16 sK[2][HALFU16];
  __shared__ __align__(16) u16 sV[2][HALFU16];

  const int tid  = threadIdx.x;
  const int lane = tid & 63;
  const int wave = tid >> 6;
  const int lr   = lane & 15;   // q-row within 16
  const int lg   = lane >> 4;   // group 0..3

  // XCD-aware swizzle: 2048 blocks, 8 XCDs -> contiguous runs of 256
  // (2 KV heads per XCD; K+V images ~1MB, L2-resident).
  const int id = blockIdx.x;           // 0..2047
  const int wg = (id & 7) * 256 + (id >> 3);
  const int qtile = wg & 31;           // 0..31
  const int bqh   = wg >> 5;           // 0..63
  const int b     = bqh >> 5;
  const int qh    = bqh & 31;
  const int kh    = qh >> 2;           // G = 4

  const size_t qbase = (size_t)bqh * SEQ * DIM;
  const u16* imgK = ws + (size_t)(b * NKH + kh) * HEADU16;
  const u16* imgV = imgK + VOFFU16;
  const int qrow0 = qtile * QT + wave * 16;

  // log2-domain scale: 1/sqrt(128) * log2(e)
  const float s2 = 0.08838834764831845f * 1.4426950408889634f;

  // Q frags: qf[s][e] = Q[q=lr][d=32s+8lg+e] * s2
  u16x8 qf[4];
  #pragma unroll
  for (int s = 0; s < 4; ++s) {
    const float* qp = Qg + qbase + (size_t)(qrow0 + lr) * DIM + 32 * s + 8 * lg;
    float4 a = *(const float4*)qp;
    float4 c = *(const float4*)(qp + 4);
    qf[s] = __builtin_bit_cast(u16x8, u32x4{
        cvtpk(a.x * s2, a.y * s2), cvtpk(a.z * s2, a.w * s2),
        cvtpk(c.x * s2, c.y * s2), cvtpk(c.z * s2, c.w * s2) });
  }

  const f32x4 zero4 = {0.f, 0.f, 0.f, 0.f};
  f32x4 oacc[8];
  #pragma unroll
  for (int dt = 0; dt < 8; ++dt) oacc[dt] = zero4;
  float mrow = -3.0e38f, lrow = 0.f;

  const int swzK = (lr & 7) << 3;
  const int swzV = (lg ^ ((lr >> 1) & 3)) << 3;

  auto issue = [&](int hn, int pb) {
    const u16* gK = imgK + (size_t)hn * HALFU16;
    const u16* gV = imgV + (size_t)hn * HALFU16;
    gl_lds16(gK + wave * 512 + lane * 8,       &sK[pb][wave * 512]);
    gl_lds16(gK + (wave + 4) * 512 + lane * 8, &sK[pb][(wave + 4) * 512]);
    gl_lds16(gV + wave * 512 + lane * 8,       &sV[pb][wave * 512]);
    gl_lds16(gV + (wave + 4) * 512 + lane * 8, &sV[pb][(wave + 4) * 512]);
  };

  auto half_body = [&](int H, int PB) {
    issue((H + 1) & (NHALF - 1), PB ^ 1);   // prefetch next half
    asm volatile("s_waitcnt vmcnt(4)" ::: "memory");  // this half's 4 loads done
    __builtin_amdgcn_s_barrier();           // keep prefetch in flight

    // ---- S^T = K Q^T : sacc[jt][e] = S[key=16jt+4lg+e][q=lr] (log2 domain)
    f32x4 sacc[2] = {zero4, zero4};
    __builtin_amdgcn_s_setprio(1);
    #pragma unroll
    for (int jt = 0; jt < 2; ++jt) {
      #pragma unroll
      for (int s = 0; s < 4; ++s) {
        u16x8 kf = *(const u16x8*)&sK[PB][(jt * 16 + lr) * 128 + ((32 * s + 8 * lg) ^ swzK)];
        sacc[jt] = mfma16(kf, qf[s], sacc[jt]);
      }
    }
    __builtin_amdgcn_s_setprio(0);

    // ---- online softmax, in-register (q-row = lr per lane)
    float tmax = sacc[0][0];
    #pragma unroll
    for (int jt = 0; jt < 2; ++jt)
      #pragma unroll
      for (int e = 0; e < 4; ++e) tmax = fmaxf(tmax, sacc[jt][e]);
    tmax = fmaxf(tmax, __shfl_xor(tmax, 16, 64));
    tmax = fmaxf(tmax, __shfl_xor(tmax, 32, 64));

    if (!__all(tmax - mrow <= 11.0f)) {     // defer-max (P bounded by 2^11)
      float mn = fmaxf(mrow, tmax);
      float corr = exp2f(mrow - mn);
      mrow = mn;
      lrow *= corr;
      float corr_o[4];
      #pragma unroll
      for (int e = 0; e < 4; ++e) corr_o[e] = __shfl(corr, 4 * lg + e, 64);
      #pragma unroll
      for (int dt = 0; dt < 8; ++dt)
        #pragma unroll
        for (int e = 0; e < 4; ++e) oacc[dt][e] *= corr_o[e];
    }

    float rsum = 0.f;
    u32 pk[4];
    #pragma unroll
    for (int jt = 0; jt < 2; ++jt) {
      float p0 = exp2f(sacc[jt][0] - mrow);
      float p1 = exp2f(sacc[jt][1] - mrow);
      float p2 = exp2f(sacc[jt][2] - mrow);
      float p3 = exp2f(sacc[jt][3] - mrow);
      rsum += (p0 + p1) + (p2 + p3);
      pk[2 * jt]     = cvtpk(p0, p1);
      pk[2 * jt + 1] = cvtpk(p2, p3);
    }
    rsum += __shfl_xor(rsum, 16, 64);
    rsum += __shfl_xor(rsum, 32, 64);
    lrow += rsum;

    // ---- A-frag: pure bitcast (sigma folded into V image)
    u16x8 af = __builtin_bit_cast(u16x8, u32x4{pk[0], pk[1], pk[2], pk[3]});

    // ---- O += P V : vf = V half image row d=16dt+lr, granule lg (swizzled)
    __builtin_amdgcn_s_setprio(1);
    #pragma unroll
    for (int dt = 0; dt < 8; ++dt) {
      u16x8 vf = *(const u16x8*)&sV[PB][(16 * dt + lr) * 32 + swzV];
      oacc[dt] = mfma16(af, vf, oacc[dt]);
    }
    __builtin_amdgcn_s_setprio(0);
    __builtin_amdgcn_s_barrier();           // all waves done reading buf[PB]
  };

  issue(0, 0);
  #pragma unroll 2
  for (int H = 0; H < NHALF; ++H) half_body(H, H & 1);
  asm volatile("s_waitcnt vmcnt(0)" ::: "memory");  // drain wrap-around prefetch

  // ---- epilogue: normalize and store; O rows are q = 4lg+e
  float linv = 1.0f / lrow;
  float linv_o[4];
  #pragma unroll
  for (int e = 0; e < 4; ++e) linv_o[e] = __shfl(linv, 4 * lg + e, 64);
  #pragma unroll
  for (int e = 0; e < 4; ++e) {
    int row = qrow0 + 4 * lg + e;
    float* op = Og + qbase + (size_t)row * DIM;
    #pragma unroll
    for (int dt = 0; dt < 8; ++dt) op[dt * 16 + lr] = oacc[dt][e] * linv_o[e];
  }
}

extern "C" void kernel_launch(void* const* d_in, const int* in_sizes, int n_in,
                              void* d_out, int out_size, void* d_ws, size_t ws_size,
                              hipStream_t stream) {
  const float* Q = (const float*)d_in[0];
  const float* K = (const float*)d_in[1];
  const float* V = (const float*)d_in[2];
  float* O = (float*)d_out;
  u16* ws = (u16*)d_ws;
  prep<<<dim3(1024), 256, 0, stream>>>(K, V, ws);
  gqa_fwd<<<dim3((SEQ / QT) * NB * NQH), 256, 0, stream>>>(Q, ws, O);
}